// Round 4
// baseline (2563.879 us; speedup 1.0000x reference)
//
#include <hip/hip_runtime.h>
#include <hip/hip_bf16.h>

#define B_ 128
#define S_ 512
#define C_ 512
#define H_ 512
#define NC_ 64
#define T_ 25
#define TEXTW (T_ + 1)

typedef __attribute__((ext_vector_type(8))) short bf16x8;
typedef __attribute__((ext_vector_type(4))) float f32x4;

__device__ __forceinline__ float bf2f(unsigned short u) {
    union { unsigned int i; float f; } v; v.i = ((unsigned int)u) << 16; return v.f;
}
__device__ __forceinline__ unsigned short f2bf(float f) {
    union { float f; unsigned int u; } v; v.f = f;
    unsigned int r = (v.u + 0x7FFFu + ((v.u >> 16) & 1u)) >> 16;
    return (unsigned short)r;
}
__device__ __forceinline__ void gload_lds16(const void* g, void* l) {
    __builtin_amdgcn_global_load_lds(
        (const __attribute__((address_space(1))) unsigned int*)g,
        (__attribute__((address_space(3))) unsigned int*)l, 16, 0, 0);
}
__device__ __forceinline__ float fast_tanh(float x) {
    float a = fabsf(x);
    float e = __builtin_amdgcn_exp2f(2.885390082f * a);
    float r = 1.f - 2.f * __builtin_amdgcn_rcpf(e + 1.f);
    return copysignf(r, x);
}
__device__ __forceinline__ float fast_sigmoid(float x) {
    return __builtin_amdgcn_rcpf(1.f + __builtin_amdgcn_exp2f(-1.442695041f * x));
}

// ---------------- init: h=c=0, hp=b_h2h, inp h-part = 0 ----------------
__global__ __launch_bounds__(512) void init_k(float* h, float* c, float* hp,
                                              const float* __restrict__ bh,
                                              unsigned short* inp) {
    int b = blockIdx.x, j = threadIdx.x;
    h[b * 512 + j] = 0.f;
    c[b * 512 + j] = 0.f;
    hp[b * 512 + j] = bh[j];
    inp[b * 1024 + 512 + j] = 0;
}

// ---------------- conversions ----------------
__global__ __launch_bounds__(256) void conv_x(const float* __restrict__ in,
                                              unsigned short* __restrict__ out) {
    int i = blockIdx.x * 256 + threadIdx.x;
    const float4 v = ((const float4*)in)[i];
    ushort4 o;
    o.x = f2bf(v.x); o.y = f2bf(v.y); o.z = f2bf(v.z); o.w = f2bf(v.w);
    ((ushort4*)out)[i] = o;
}

__global__ __launch_bounds__(512) void conv_wt(const float* __restrict__ in,
                                               unsigned short* __restrict__ out) {
    int n = blockIdx.x, k = threadIdx.x;
    out[n * 512 + k] = f2bf(in[k * 512 + n]);
}

__global__ __launch_bounds__(512) void conv_wh(const float* __restrict__ in,
                                               unsigned short* __restrict__ out) {
    int i = blockIdx.x * 512 + threadIdx.x;
    out[i] = f2bf(in[i]);
}

// WU_t [n'=h*4+g][k=1024] bf16
__global__ __launch_bounds__(256) void conv_wut(const float* __restrict__ W,
                                                const float* __restrict__ U,
                                                unsigned short* __restrict__ out) {
    int np = blockIdx.x;
    int h = np >> 2, g = np & 3;
    for (int k = threadIdx.x; k < 1024; k += 256) {
        float v = (k < 512) ? W[(size_t)k * 2048 + g * 512 + h]
                            : U[(size_t)(k - 512) * 2048 + g * 512 + h];
        out[(size_t)np * 1024 + k] = f2bf(v);
    }
}

// ---------------- proj = x @ W_i2h via MFMA (bf16), XCD-chunked swizzle ----------------
__global__ __launch_bounds__(256) void gemm_proj(const unsigned short* __restrict__ A,
                                                 const unsigned short* __restrict__ Bt,
                                                 unsigned short* __restrict__ Cm) {
    __shared__ unsigned short As[128 * 64];
    __shared__ unsigned short Bs[128 * 64];
    int tid = threadIdx.x;
    int lane = tid & 63;
    int wid = tid >> 6;
    int wr = wid >> 1, wc = wid & 1;
    // bijective XCD swizzle: nwg = 2048, 256 per XCD chunk
    int wg = blockIdx.y * 4 + blockIdx.x;
    int swz = (wg % 8) * 256 + wg / 8;
    int row0 = (swz >> 2) * 128;
    int col0 = (swz & 3) * 128;

    f32x4 acc[4][4];
#pragma unroll
    for (int i = 0; i < 4; ++i)
#pragma unroll
        for (int j = 0; j < 4; ++j) acc[i][j] = (f32x4){0.f, 0.f, 0.f, 0.f};

    for (int k0 = 0; k0 < 512; k0 += 64) {
#pragma unroll
        for (int i = 0; i < 4; ++i) {
            int e = tid + i * 256;
            int r = e >> 3, cc = e & 7;
            int cs = cc ^ (r & 7);
            gload_lds16(A + (size_t)(row0 + r) * 512 + k0 + cs * 8, &As[e * 8]);
        }
#pragma unroll
        for (int i = 0; i < 4; ++i) {
            int e = tid + i * 256;
            int r = e >> 3, cc = e & 7;
            int cs = cc ^ (r & 7);
            gload_lds16(Bt + (size_t)(col0 + r) * 512 + k0 + cs * 8, &Bs[e * 8]);
        }
        __syncthreads();
#pragma unroll
        for (int ks = 0; ks < 2; ++ks) {
            bf16x8 a[4], b[4];
#pragma unroll
            for (int i = 0; i < 4; ++i) {
                int m = wr * 64 + i * 16 + (lane & 15);
                int ch = (ks * 4 + (lane >> 4)) ^ (m & 7);
                a[i] = *(const bf16x8*)&As[(m * 8 + ch) * 8];
            }
#pragma unroll
            for (int j = 0; j < 4; ++j) {
                int n = wc * 64 + j * 16 + (lane & 15);
                int ch = (ks * 4 + (lane >> 4)) ^ (n & 7);
                b[j] = *(const bf16x8*)&Bs[(n * 8 + ch) * 8];
            }
#pragma unroll
            for (int i = 0; i < 4; ++i)
#pragma unroll
                for (int j = 0; j < 4; ++j)
                    acc[i][j] = __builtin_amdgcn_mfma_f32_16x16x32_bf16(a[i], b[j], acc[i][j], 0, 0, 0);
        }
        __syncthreads();
    }
#pragma unroll
    for (int i = 0; i < 4; ++i)
#pragma unroll
        for (int j = 0; j < 4; ++j) {
            int gcol = col0 + wc * 64 + j * 16 + (lane & 15);
#pragma unroll
            for (int r = 0; r < 4; ++r) {
                int grow = row0 + wr * 64 + i * 16 + (lane >> 4) * 4 + r;
                Cm[(size_t)grow * 512 + gcol] = f2bf(acc[i][j][r]);
            }
        }
}

// ---------------- zgates: z = inp @ WU_t^T + gate math + state update ----------------
// grid 16 blocks x 256 threads; block covers all 128 b x 128 n' (32 h, 4 gates)
__global__ __launch_bounds__(256) void zgates(
    const unsigned short* __restrict__ A, const unsigned short* __restrict__ Bt,
    const int* __restrict__ text, const float* __restrict__ Wl,
    const float* __restrict__ bl,
    float* __restrict__ c, float* __restrict__ h,
    float* __restrict__ hs_t, unsigned short* __restrict__ inp, int t) {
    __shared__ union U {
        struct { unsigned short As[128 * 64]; unsigned short Bs[128 * 64]; } s;
        float zt[128][130];
    } u;
    int tid = threadIdx.x;
    int lane = tid & 63;
    int wid = tid >> 6;
    int wr = wid >> 1, wc = wid & 1;
    int col0 = blockIdx.x * 128;

    f32x4 acc[4][4];
#pragma unroll
    for (int i = 0; i < 4; ++i)
#pragma unroll
        for (int j = 0; j < 4; ++j) acc[i][j] = (f32x4){0.f, 0.f, 0.f, 0.f};

    for (int k0 = 0; k0 < 1024; k0 += 64) {
#pragma unroll
        for (int i = 0; i < 4; ++i) {
            int e = tid + i * 256;
            int r = e >> 3, cc = e & 7;
            int cs = cc ^ (r & 7);
            gload_lds16(A + (size_t)r * 1024 + k0 + cs * 8, &u.s.As[e * 8]);
        }
#pragma unroll
        for (int i = 0; i < 4; ++i) {
            int e = tid + i * 256;
            int r = e >> 3, cc = e & 7;
            int cs = cc ^ (r & 7);
            gload_lds16(Bt + (size_t)(col0 + r) * 1024 + k0 + cs * 8, &u.s.Bs[e * 8]);
        }
        __syncthreads();
#pragma unroll
        for (int ks = 0; ks < 2; ++ks) {
            bf16x8 a[4], b[4];
#pragma unroll
            for (int i = 0; i < 4; ++i) {
                int m = wr * 64 + i * 16 + (lane & 15);
                int ch = (ks * 4 + (lane >> 4)) ^ (m & 7);
                a[i] = *(const bf16x8*)&u.s.As[(m * 8 + ch) * 8];
            }
#pragma unroll
            for (int j = 0; j < 4; ++j) {
                int n = wc * 64 + j * 16 + (lane & 15);
                int ch = (ks * 4 + (lane >> 4)) ^ (n & 7);
                b[j] = *(const bf16x8*)&u.s.Bs[(n * 8 + ch) * 8];
            }
#pragma unroll
            for (int i = 0; i < 4; ++i)
#pragma unroll
                for (int j = 0; j < 4; ++j)
                    acc[i][j] = __builtin_amdgcn_mfma_f32_16x16x32_bf16(a[i], b[j], acc[i][j], 0, 0, 0);
        }
        __syncthreads();
    }
    // stage z tile in LDS (stride 130 -> <=2-way write aliasing)
#pragma unroll
    for (int i = 0; i < 4; ++i)
#pragma unroll
        for (int j = 0; j < 4; ++j) {
            int gcolL = wc * 64 + j * 16 + (lane & 15);
#pragma unroll
            for (int r = 0; r < 4; ++r) {
                int grow = wr * 64 + i * 16 + (lane >> 4) * 4 + r;
                u.zt[grow][gcolL] = acc[i][j][r];
            }
        }
    __syncthreads();
    // gate phase: 4096 (b, hl) items, 16 per thread; b-major for coalesced global writes
#pragma unroll
    for (int it = 0; it < 16; ++it) {
        int item = tid + it * 256;
        int b = item >> 5;          // 0..127
        int hl = item & 31;         // 0..31
        int hg = (col0 >> 2) + hl;  // global h
        int ch = text[b * TEXTW + t];
        const float* wrow = Wl + (size_t)(512 + ch) * 2048;
        float zi = u.zt[b][hl * 4 + 0] + bl[hg] + wrow[hg];
        float zf = u.zt[b][hl * 4 + 1] + bl[512 + hg] + wrow[512 + hg];
        float zg = u.zt[b][hl * 4 + 2] + bl[1024 + hg] + wrow[1024 + hg];
        float zo = u.zt[b][hl * 4 + 3] + bl[1536 + hg] + wrow[1536 + hg];
        float ig = fast_sigmoid(zi);
        float fg = fast_sigmoid(zf);
        float gg = fast_tanh(zg);
        float og = fast_sigmoid(zo);
        int idx = b * 512 + hg;
        float cn = fg * c[idx] + ig * gg;
        float hn = og * fast_tanh(cn);
        c[idx] = cn;
        h[idx] = hn;
        hs_t[idx] = hn;
        inp[b * 1024 + 512 + hg] = f2bf(hn);
    }
}

// ---------------- e[b,s] = tanh(proj[b,s,:]+hp[b,:]) . Wscore ----------------
__global__ __launch_bounds__(256) void e_kernel(
    const unsigned short* __restrict__ proj, const float* __restrict__ hp,
    const float* __restrict__ Wscore, float* __restrict__ e_buf) {
    int b = blockIdx.y, sc = blockIdx.x;
    int tid = threadIdx.x, wave = tid >> 6, lane = tid & 63;
    float4 h0 = *(const float4*)(hp + b * 512 + lane * 8);
    float4 h1 = *(const float4*)(hp + b * 512 + lane * 8 + 4);
    float4 w0 = *(const float4*)(Wscore + lane * 8);
    float4 w1 = *(const float4*)(Wscore + lane * 8 + 4);
    float hp_r[8] = {h0.x, h0.y, h0.z, h0.w, h1.x, h1.y, h1.z, h1.w};
    float w_r[8]  = {w0.x, w0.y, w0.z, w0.w, w1.x, w1.y, w1.z, w1.w};
    int s0 = sc * 64 + wave * 16;
    for (int i = 0; i < 16; ++i) {
        int s = s0 + i;
        const bf16x8 pv = *(const bf16x8*)(proj + ((size_t)(b * 512 + s) << 9) + lane * 8);
        float a = 0.f;
#pragma unroll
        for (int j = 0; j < 8; ++j)
            a += fast_tanh(bf2f((unsigned short)pv[j]) + hp_r[j]) * w_r[j];
#pragma unroll
        for (int off = 32; off > 0; off >>= 1) a += __shfl_xor(a, off, 64);
        if (lane == 0) e_buf[b * 512 + s] = a;
    }
}

// ---------------- softmax(e) + context -> inp_bf[b][0..512) ----------------
// grid (cc=2, b=128), 512 threads; lane owns 4 contiguous cols (ushort4)
__global__ __launch_bounds__(512) void ctx_kernel(
    const float* __restrict__ e_buf, const unsigned short* __restrict__ xb,
    unsigned short* __restrict__ inp) {
    __shared__ float sh_alpha[512];
    __shared__ float sh_red[16];
    __shared__ float shp[8][256];
    int b = blockIdx.y, cc = blockIdx.x;
    int tid = threadIdx.x, wave = tid >> 6, lane = tid & 63;
    float v = e_buf[b * 512 + tid];
    float m = v;
#pragma unroll
    for (int off = 32; off > 0; off >>= 1) m = fmaxf(m, __shfl_xor(m, off, 64));
    if (lane == 0) sh_red[wave] = m;
    __syncthreads();
    float mm = sh_red[0];
#pragma unroll
    for (int i = 1; i < 8; ++i) mm = fmaxf(mm, sh_red[i]);
    float p = __builtin_amdgcn_exp2f(1.442695041f * (v - mm));
    float ss = p;
#pragma unroll
    for (int off = 32; off > 0; off >>= 1) ss += __shfl_xor(ss, off, 64);
    if (lane == 0) sh_red[8 + wave] = ss;
    __syncthreads();
    float tot = 0.f;
#pragma unroll
    for (int i = 0; i < 8; ++i) tot += sh_red[8 + i];
    sh_alpha[tid] = p / tot;
    __syncthreads();
    int colL = lane * 4;
    int col = cc * 256 + colL;
    float a0 = 0.f, a1 = 0.f, a2 = 0.f, a3 = 0.f;
    for (int s = wave; s < 512; s += 8) {
        float al = sh_alpha[s];
        ushort4 xv = *(const ushort4*)(xb + ((size_t)(b * 512 + s) << 9) + col);
        a0 += al * bf2f(xv.x);
        a1 += al * bf2f(xv.y);
        a2 += al * bf2f(xv.z);
        a3 += al * bf2f(xv.w);
    }
    *(float4*)&shp[wave][colL] = make_float4(a0, a1, a2, a3);
    __syncthreads();
    if (tid < 256) {
        float s = 0.f;
#pragma unroll
        for (int r = 0; r < 8; ++r) s += shp[r][tid];
        inp[b * 1024 + cc * 256 + tid] = f2bf(s);
    }
}

// ---------------- hp = h @ W_h2h + b_h2h ----------------
// grid (jc=2, b=128), 256 threads; lane owns 4 contiguous cols
__global__ __launch_bounds__(256) void hp_kernel(
    const float* __restrict__ h, const unsigned short* __restrict__ Whb,
    const float* __restrict__ bh2h, float* __restrict__ hp) {
    __shared__ float sh_h[512];
    __shared__ float shp[4][256];
    int b = blockIdx.y, jc = blockIdx.x;
    int tid = threadIdx.x, wave = tid >> 6, lane = tid & 63;
    sh_h[tid] = h[b * 512 + tid];
    sh_h[256 + tid] = h[b * 512 + 256 + tid];
    __syncthreads();
    int colL = lane * 4;
    int col = jc * 256 + colL;
    float a0 = 0.f, a1 = 0.f, a2 = 0.f, a3 = 0.f;
    for (int k = wave * 128; k < wave * 128 + 128; ++k) {
        float hv = sh_h[k];
        ushort4 w = *(const ushort4*)(Whb + k * 512 + col);
        a0 += hv * bf2f(w.x);
        a1 += hv * bf2f(w.y);
        a2 += hv * bf2f(w.z);
        a3 += hv * bf2f(w.w);
    }
    *(float4*)&shp[wave][colL] = make_float4(a0, a1, a2, a3);
    __syncthreads();
    // 256 threads: one col each
    {
        float s = bh2h[jc * 256 + tid];
#pragma unroll
        for (int r = 0; r < 4; ++r) s += shp[r][tid];
        hp[b * 512 + jc * 256 + tid] = s;
    }
}

// ---------------- probs = hs @ W_gen + b_gen ----------------
__global__ __launch_bounds__(64) void gen_probs(const float* __restrict__ hs,
                                                const float* __restrict__ Wg,
                                                const float* __restrict__ bg,
                                                float* __restrict__ out) {
    __shared__ float sh[512];
    int bt = blockIdx.x;
    int b = bt / T_, t = bt % T_;
    int tid = threadIdx.x;
    const float* hrow = hs + ((size_t)t * B_ + b) * H_;
    for (int i = tid; i < 512; i += 64) sh[i] = hrow[i];
    __syncthreads();
    float acc = bg[tid];
#pragma unroll 4
    for (int k = 0; k < 512; ++k) acc += sh[k] * Wg[k * 64 + tid];
    out[(size_t)bt * 64 + tid] = acc;
}

extern "C" void kernel_launch(void* const* d_in, const int* in_sizes, int n_in,
                              void* d_out, int out_size, void* d_ws, size_t ws_size,
                              hipStream_t stream) {
    const float* x       = (const float*)d_in[0];
    const int*   text    = (const int*)d_in[1];
    const float* W_i2h   = (const float*)d_in[2];
    const float* W_h2h   = (const float*)d_in[3];
    const float* b_h2h   = (const float*)d_in[4];
    const float* W_score = (const float*)d_in[5];
    const float* W_lstm  = (const float*)d_in[6];
    const float* U_lstm  = (const float*)d_in[7];
    const float* b_lstm  = (const float*)d_in[8];
    const float* W_gen   = (const float*)d_in[9];
    const float* b_gen   = (const float*)d_in[10];
    float* out = (float*)d_out;

    char* ws = (char*)d_ws;
    unsigned short* x_bf    = (unsigned short*)ws;                 // 67,108,864
    unsigned short* proj_bf = (unsigned short*)(ws + 67108864);    // 67,108,864
    unsigned short* Wt_bf   = (unsigned short*)(ws + 134217728);   //    524,288
    unsigned short* Wh_bf   = (unsigned short*)(ws + 134742016);   //    524,288
    unsigned short* WU_t    = (unsigned short*)(ws + 135266304);   //  4,194,304
    float* h       = (float*)(ws + 139460608);
    float* c       = (float*)(ws + 139722752);
    float* hp_buf  = (float*)(ws + 139984896);
    float* e_buf   = (float*)(ws + 140247040);
    unsigned short* inp_bf = (unsigned short*)(ws + 140509184);
    float* z_unused = (float*)(ws + 140771328);
    float* hs      = (float*)(ws + 141819904);                     // 13,107,200

    (void)z_unused;
    init_k<<<dim3(128), 512, 0, stream>>>(h, c, hp_buf, b_h2h, inp_bf);
    conv_x<<<dim3(32768), 256, 0, stream>>>(x, x_bf);
    conv_wt<<<dim3(512), 512, 0, stream>>>(W_i2h, Wt_bf);
    conv_wh<<<dim3(512), 512, 0, stream>>>(W_h2h, Wh_bf);
    conv_wut<<<dim3(2048), 256, 0, stream>>>(W_lstm, U_lstm, WU_t);
    gemm_proj<<<dim3(4, 512), 256, 0, stream>>>(x_bf, Wt_bf, proj_bf);
    for (int t = 0; t < T_; ++t) {
        e_kernel<<<dim3(8, 128), 256, 0, stream>>>(proj_bf, hp_buf, W_score, e_buf);
        ctx_kernel<<<dim3(2, 128), 512, 0, stream>>>(e_buf, x_bf, inp_bf);
        zgates<<<dim3(16), 256, 0, stream>>>(inp_bf, WU_t, text, W_lstm, b_lstm,
                                             c, h, hs + (size_t)t * (B_ * H_), inp_bf, t);
        if (t < T_ - 1)
            hp_kernel<<<dim3(2, 128), 256, 0, stream>>>(h, Wh_bf, b_h2h, hp_buf);
    }
    gen_probs<<<dim3(B_ * T_), 64, 0, stream>>>(hs, W_gen, b_gen, out);
}

// Round 5
// 1882.883 us; speedup vs baseline: 1.3617x; 1.3617x over previous
//
#include <hip/hip_runtime.h>
#include <hip/hip_bf16.h>

#define B_ 128
#define S_ 512
#define C_ 512
#define H_ 512
#define NC_ 64
#define T_ 25
#define TEXTW (T_ + 1)

typedef __attribute__((ext_vector_type(8))) short bf16x8;
typedef __attribute__((ext_vector_type(4))) float f32x4;

__device__ __forceinline__ float bf2f(unsigned short u) {
    union { unsigned int i; float f; } v; v.i = ((unsigned int)u) << 16; return v.f;
}
__device__ __forceinline__ unsigned short f2bf(float f) {
    union { float f; unsigned int u; } v; v.f = f;
    unsigned int r = (v.u + 0x7FFFu + ((v.u >> 16) & 1u)) >> 16;
    return (unsigned short)r;
}
__device__ __forceinline__ void gload_lds16(const void* g, void* l) {
    __builtin_amdgcn_global_load_lds(
        (const __attribute__((address_space(1))) unsigned int*)g,
        (__attribute__((address_space(3))) unsigned int*)l, 16, 0, 0);
}
__device__ __forceinline__ float fast_tanh(float x) {
    float a = fabsf(x);
    float e = __builtin_amdgcn_exp2f(2.885390082f * a);
    float r = 1.f - 2.f * __builtin_amdgcn_rcpf(e + 1.f);
    return copysignf(r, x);
}
__device__ __forceinline__ float fast_sigmoid(float x) {
    return __builtin_amdgcn_rcpf(1.f + __builtin_amdgcn_exp2f(-1.442695041f * x));
}

// ---------------- init: h=c=0, hp=b_h2h, inp h-part = 0 ----------------
__global__ __launch_bounds__(512) void init_k(float* h, float* c, float* hp,
                                              const float* __restrict__ bh,
                                              unsigned short* inp) {
    int b = blockIdx.x, j = threadIdx.x;
    h[b * 512 + j] = 0.f;
    c[b * 512 + j] = 0.f;
    hp[b * 512 + j] = bh[j];
    inp[b * 1024 + 512 + j] = 0;
}

// ---------------- conversions ----------------
__global__ __launch_bounds__(256) void conv_x(const float* __restrict__ in,
                                              unsigned short* __restrict__ out) {
    int i = blockIdx.x * 256 + threadIdx.x;
    const float4 v = ((const float4*)in)[i];
    ushort4 o;
    o.x = f2bf(v.x); o.y = f2bf(v.y); o.z = f2bf(v.z); o.w = f2bf(v.w);
    ((ushort4*)out)[i] = o;
}

__global__ __launch_bounds__(512) void conv_wt(const float* __restrict__ in,
                                               unsigned short* __restrict__ out) {
    int n = blockIdx.x, k = threadIdx.x;
    out[n * 512 + k] = f2bf(in[k * 512 + n]);
}

__global__ __launch_bounds__(512) void conv_wh(const float* __restrict__ in,
                                               unsigned short* __restrict__ out) {
    int i = blockIdx.x * 512 + threadIdx.x;
    out[i] = f2bf(in[i]);
}

// WU_t [n'=h*4+g][k=1024] bf16
__global__ __launch_bounds__(256) void conv_wut(const float* __restrict__ W,
                                                const float* __restrict__ U,
                                                unsigned short* __restrict__ out) {
    int np = blockIdx.x;
    int h = np >> 2, g = np & 3;
    for (int k = threadIdx.x; k < 1024; k += 256) {
        float v = (k < 512) ? W[(size_t)k * 2048 + g * 512 + h]
                            : U[(size_t)(k - 512) * 2048 + g * 512 + h];
        out[(size_t)np * 1024 + k] = f2bf(v);
    }
}

// ---------------- proj = x @ W_i2h via MFMA (bf16) ----------------
__global__ __launch_bounds__(256) void gemm_proj(const unsigned short* __restrict__ A,
                                                 const unsigned short* __restrict__ Bt,
                                                 unsigned short* __restrict__ Cm) {
    __shared__ unsigned short As[128 * 64];
    __shared__ unsigned short Bs[128 * 64];
    int tid = threadIdx.x;
    int lane = tid & 63;
    int wid = tid >> 6;
    int wr = wid >> 1, wc = wid & 1;
    int row0 = blockIdx.y * 128;
    int col0 = blockIdx.x * 128;

    f32x4 acc[4][4];
#pragma unroll
    for (int i = 0; i < 4; ++i)
#pragma unroll
        for (int j = 0; j < 4; ++j) acc[i][j] = (f32x4){0.f, 0.f, 0.f, 0.f};

    for (int k0 = 0; k0 < 512; k0 += 64) {
#pragma unroll
        for (int i = 0; i < 4; ++i) {
            int e = tid + i * 256;
            int r = e >> 3, cc = e & 7;
            int cs = cc ^ (r & 7);
            gload_lds16(A + (size_t)(row0 + r) * 512 + k0 + cs * 8, &As[e * 8]);
        }
#pragma unroll
        for (int i = 0; i < 4; ++i) {
            int e = tid + i * 256;
            int r = e >> 3, cc = e & 7;
            int cs = cc ^ (r & 7);
            gload_lds16(Bt + (size_t)(col0 + r) * 512 + k0 + cs * 8, &Bs[e * 8]);
        }
        __syncthreads();
#pragma unroll
        for (int ks = 0; ks < 2; ++ks) {
            bf16x8 a[4], b[4];
#pragma unroll
            for (int i = 0; i < 4; ++i) {
                int m = wr * 64 + i * 16 + (lane & 15);
                int ch = (ks * 4 + (lane >> 4)) ^ (m & 7);
                a[i] = *(const bf16x8*)&As[(m * 8 + ch) * 8];
            }
#pragma unroll
            for (int j = 0; j < 4; ++j) {
                int n = wc * 64 + j * 16 + (lane & 15);
                int ch = (ks * 4 + (lane >> 4)) ^ (n & 7);
                b[j] = *(const bf16x8*)&Bs[(n * 8 + ch) * 8];
            }
#pragma unroll
            for (int i = 0; i < 4; ++i)
#pragma unroll
                for (int j = 0; j < 4; ++j)
                    acc[i][j] = __builtin_amdgcn_mfma_f32_16x16x32_bf16(a[i], b[j], acc[i][j], 0, 0, 0);
        }
        __syncthreads();
    }
#pragma unroll
    for (int i = 0; i < 4; ++i)
#pragma unroll
        for (int j = 0; j < 4; ++j) {
            int gcol = col0 + wc * 64 + j * 16 + (lane & 15);
#pragma unroll
            for (int r = 0; r < 4; ++r) {
                int grow = row0 + wr * 64 + i * 16 + (lane >> 4) * 4 + r;
                Cm[(size_t)grow * 512 + gcol] = f2bf(acc[i][j][r]);
            }
        }
}

// ---------------- z = inp @ WU_t^T  (M=128, N'=2048, K=1024) ----------------
__global__ __launch_bounds__(256) void z_gemm(const unsigned short* __restrict__ A,
                                              const unsigned short* __restrict__ Bt,
                                              float* __restrict__ Z) {
    __shared__ unsigned short As[128 * 64];
    __shared__ unsigned short Bs[128 * 64];
    int tid = threadIdx.x;
    int lane = tid & 63;
    int wid = tid >> 6;
    int wr = wid >> 1, wc = wid & 1;
    int col0 = blockIdx.x * 128;

    f32x4 acc[4][4];
#pragma unroll
    for (int i = 0; i < 4; ++i)
#pragma unroll
        for (int j = 0; j < 4; ++j) acc[i][j] = (f32x4){0.f, 0.f, 0.f, 0.f};

    for (int k0 = 0; k0 < 1024; k0 += 64) {
#pragma unroll
        for (int i = 0; i < 4; ++i) {
            int e = tid + i * 256;
            int r = e >> 3, cc = e & 7;
            int cs = cc ^ (r & 7);
            gload_lds16(A + (size_t)r * 1024 + k0 + cs * 8, &As[e * 8]);
        }
#pragma unroll
        for (int i = 0; i < 4; ++i) {
            int e = tid + i * 256;
            int r = e >> 3, cc = e & 7;
            int cs = cc ^ (r & 7);
            gload_lds16(Bt + (size_t)(col0 + r) * 1024 + k0 + cs * 8, &Bs[e * 8]);
        }
        __syncthreads();
#pragma unroll
        for (int ks = 0; ks < 2; ++ks) {
            bf16x8 a[4], b[4];
#pragma unroll
            for (int i = 0; i < 4; ++i) {
                int m = wr * 64 + i * 16 + (lane & 15);
                int ch = (ks * 4 + (lane >> 4)) ^ (m & 7);
                a[i] = *(const bf16x8*)&As[(m * 8 + ch) * 8];
            }
#pragma unroll
            for (int j = 0; j < 4; ++j) {
                int n = wc * 64 + j * 16 + (lane & 15);
                int ch = (ks * 4 + (lane >> 4)) ^ (n & 7);
                b[j] = *(const bf16x8*)&Bs[(n * 8 + ch) * 8];
            }
#pragma unroll
            for (int i = 0; i < 4; ++i)
#pragma unroll
                for (int j = 0; j < 4; ++j)
                    acc[i][j] = __builtin_amdgcn_mfma_f32_16x16x32_bf16(a[i], b[j], acc[i][j], 0, 0, 0);
        }
        __syncthreads();
    }
#pragma unroll
    for (int i = 0; i < 4; ++i)
#pragma unroll
        for (int j = 0; j < 4; ++j) {
            int gcol = col0 + wc * 64 + j * 16 + (lane & 15);
#pragma unroll
            for (int r = 0; r < 4; ++r) {
                int grow = wr * 64 + i * 16 + (lane >> 4) * 4 + r;
                Z[(size_t)grow * 2048 + gcol] = acc[i][j][r];
            }
        }
}

// ---------------- e[b,s] = tanh(proj[b,s,:]+hp[b,:]) . Wscore ----------------
__global__ __launch_bounds__(256) void e_kernel(
    const unsigned short* __restrict__ proj, const float* __restrict__ hp,
    const float* __restrict__ Wscore, float* __restrict__ e_buf) {
    int b = blockIdx.y, sc = blockIdx.x;
    int tid = threadIdx.x, wave = tid >> 6, lane = tid & 63;
    float4 h0 = *(const float4*)(hp + b * 512 + lane * 8);
    float4 h1 = *(const float4*)(hp + b * 512 + lane * 8 + 4);
    float4 w0 = *(const float4*)(Wscore + lane * 8);
    float4 w1 = *(const float4*)(Wscore + lane * 8 + 4);
    float hp_r[8] = {h0.x, h0.y, h0.z, h0.w, h1.x, h1.y, h1.z, h1.w};
    float w_r[8]  = {w0.x, w0.y, w0.z, w0.w, w1.x, w1.y, w1.z, w1.w};
    int s0 = sc * 64 + wave * 16;
    for (int i = 0; i < 16; ++i) {
        int s = s0 + i;
        const bf16x8 pv = *(const bf16x8*)(proj + ((size_t)(b * 512 + s) << 9) + lane * 8);
        float a = 0.f;
#pragma unroll
        for (int j = 0; j < 8; ++j)
            a += fast_tanh(bf2f((unsigned short)pv[j]) + hp_r[j]) * w_r[j];
#pragma unroll
        for (int off = 32; off > 0; off >>= 1) a += __shfl_xor(a, off, 64);
        if (lane == 0) e_buf[b * 512 + s] = a;
    }
}

// ---------------- softmax(e) + context -> inp_bf[b][0..512) ----------------
// grid (cc=2, b=128), 512 threads; lane owns 4 contiguous cols (ushort4)
__global__ __launch_bounds__(512) void ctx_kernel(
    const float* __restrict__ e_buf, const unsigned short* __restrict__ xb,
    unsigned short* __restrict__ inp) {
    __shared__ float sh_alpha[512];
    __shared__ float sh_red[16];
    __shared__ float shp[8][256];
    int b = blockIdx.y, cc = blockIdx.x;
    int tid = threadIdx.x, wave = tid >> 6, lane = tid & 63;
    float v = e_buf[b * 512 + tid];
    float m = v;
#pragma unroll
    for (int off = 32; off > 0; off >>= 1) m = fmaxf(m, __shfl_xor(m, off, 64));
    if (lane == 0) sh_red[wave] = m;
    __syncthreads();
    float mm = sh_red[0];
#pragma unroll
    for (int i = 1; i < 8; ++i) mm = fmaxf(mm, sh_red[i]);
    float p = __builtin_amdgcn_exp2f(1.442695041f * (v - mm));
    float ss = p;
#pragma unroll
    for (int off = 32; off > 0; off >>= 1) ss += __shfl_xor(ss, off, 64);
    if (lane == 0) sh_red[8 + wave] = ss;
    __syncthreads();
    float tot = 0.f;
#pragma unroll
    for (int i = 0; i < 8; ++i) tot += sh_red[8 + i];
    sh_alpha[tid] = p / tot;
    __syncthreads();
    int colL = lane * 4;
    int col = cc * 256 + colL;
    float a0 = 0.f, a1 = 0.f, a2 = 0.f, a3 = 0.f;
    for (int s = wave; s < 512; s += 8) {
        float al = sh_alpha[s];
        ushort4 xv = *(const ushort4*)(xb + ((size_t)(b * 512 + s) << 9) + col);
        a0 += al * bf2f(xv.x);
        a1 += al * bf2f(xv.y);
        a2 += al * bf2f(xv.z);
        a3 += al * bf2f(xv.w);
    }
    *(float4*)&shp[wave][colL] = make_float4(a0, a1, a2, a3);
    __syncthreads();
    if (tid < 256) {
        float s = 0.f;
#pragma unroll
        for (int r = 0; r < 8; ++r) s += shp[r][tid];
        inp[b * 1024 + cc * 256 + tid] = f2bf(s);
    }
}

// ---------------- gates: z -> (h,c,hs, inp h-part) ----------------
__global__ __launch_bounds__(512) void gates_kernel(
    const float* __restrict__ z, const int* __restrict__ text,
    const float* __restrict__ Wl, const float* __restrict__ bl,
    float* __restrict__ c, float* __restrict__ h,
    float* __restrict__ hs_t, unsigned short* __restrict__ inp, int t) {
    int b = blockIdx.x, hh = threadIdx.x;
    int ch = text[b * TEXTW + t];
    const float* wrow = Wl + (size_t)(512 + ch) * 2048;
    float4 zv = *(const float4*)(z + (size_t)b * 2048 + hh * 4);
    float zi = zv.x + bl[hh] + wrow[hh];
    float zf = zv.y + bl[512 + hh] + wrow[512 + hh];
    float zg = zv.z + bl[1024 + hh] + wrow[1024 + hh];
    float zo = zv.w + bl[1536 + hh] + wrow[1536 + hh];
    float ig = fast_sigmoid(zi);
    float fg = fast_sigmoid(zf);
    float gg = fast_tanh(zg);
    float og = fast_sigmoid(zo);
    int idx = b * 512 + hh;
    float cn = fg * c[idx] + ig * gg;
    float hn = og * fast_tanh(cn);
    c[idx] = cn;
    h[idx] = hn;
    hs_t[idx] = hn;
    inp[b * 1024 + 512 + hh] = f2bf(hn);
}

// ---------------- hp = h @ W_h2h + b_h2h ----------------
// grid (jc=2, b=128), 256 threads; lane owns 4 contiguous cols
__global__ __launch_bounds__(256) void hp_kernel(
    const float* __restrict__ h, const unsigned short* __restrict__ Whb,
    const float* __restrict__ bh2h, float* __restrict__ hp) {
    __shared__ float sh_h[512];
    __shared__ float shp[4][256];
    int b = blockIdx.y, jc = blockIdx.x;
    int tid = threadIdx.x, wave = tid >> 6, lane = tid & 63;
    sh_h[tid] = h[b * 512 + tid];
    sh_h[256 + tid] = h[b * 512 + 256 + tid];
    __syncthreads();
    int colL = lane * 4;
    int col = jc * 256 + colL;
    float a0 = 0.f, a1 = 0.f, a2 = 0.f, a3 = 0.f;
    for (int k = wave * 128; k < wave * 128 + 128; ++k) {
        float hv = sh_h[k];
        ushort4 w = *(const ushort4*)(Whb + k * 512 + col);
        a0 += hv * bf2f(w.x);
        a1 += hv * bf2f(w.y);
        a2 += hv * bf2f(w.z);
        a3 += hv * bf2f(w.w);
    }
    *(float4*)&shp[wave][colL] = make_float4(a0, a1, a2, a3);
    __syncthreads();
    {
        float s = bh2h[jc * 256 + tid];
#pragma unroll
        for (int r = 0; r < 4; ++r) s += shp[r][tid];
        hp[b * 512 + jc * 256 + tid] = s;
    }
}

// ---------------- probs = hs @ W_gen + b_gen ----------------
__global__ __launch_bounds__(64) void gen_probs(const float* __restrict__ hs,
                                                const float* __restrict__ Wg,
                                                const float* __restrict__ bg,
                                                float* __restrict__ out) {
    __shared__ float sh[512];
    int bt = blockIdx.x;
    int b = bt / T_, t = bt % T_;
    int tid = threadIdx.x;
    const float* hrow = hs + ((size_t)t * B_ + b) * H_;
    for (int i = tid; i < 512; i += 64) sh[i] = hrow[i];
    __syncthreads();
    float acc = bg[tid];
#pragma unroll 4
    for (int k = 0; k < 512; ++k) acc += sh[k] * Wg[k * 64 + tid];
    out[(size_t)bt * 64 + tid] = acc;
}

extern "C" void kernel_launch(void* const* d_in, const int* in_sizes, int n_in,
                              void* d_out, int out_size, void* d_ws, size_t ws_size,
                              hipStream_t stream) {
    const float* x       = (const float*)d_in[0];
    const int*   text    = (const int*)d_in[1];
    const float* W_i2h   = (const float*)d_in[2];
    const float* W_h2h   = (const float*)d_in[3];
    const float* b_h2h   = (const float*)d_in[4];
    const float* W_score = (const float*)d_in[5];
    const float* W_lstm  = (const float*)d_in[6];
    const float* U_lstm  = (const float*)d_in[7];
    const float* b_lstm  = (const float*)d_in[8];
    const float* W_gen   = (const float*)d_in[9];
    const float* b_gen   = (const float*)d_in[10];
    float* out = (float*)d_out;

    char* ws = (char*)d_ws;
    unsigned short* x_bf    = (unsigned short*)ws;                 // 67,108,864
    unsigned short* proj_bf = (unsigned short*)(ws + 67108864);    // 67,108,864
    unsigned short* Wt_bf   = (unsigned short*)(ws + 134217728);   //    524,288
    unsigned short* Wh_bf   = (unsigned short*)(ws + 134742016);   //    524,288
    unsigned short* WU_t    = (unsigned short*)(ws + 135266304);   //  4,194,304
    float* h       = (float*)(ws + 139460608);
    float* c       = (float*)(ws + 139722752);
    float* hp_buf  = (float*)(ws + 139984896);
    float* e_buf   = (float*)(ws + 140247040);
    unsigned short* inp_bf = (unsigned short*)(ws + 140509184);
    float* z_buf   = (float*)(ws + 140771328);
    float* hs      = (float*)(ws + 141819904);                     // 13,107,200

    init_k<<<dim3(128), 512, 0, stream>>>(h, c, hp_buf, b_h2h, inp_bf);
    conv_x<<<dim3(32768), 256, 0, stream>>>(x, x_bf);
    conv_wt<<<dim3(512), 512, 0, stream>>>(W_i2h, Wt_bf);
    conv_wh<<<dim3(512), 512, 0, stream>>>(W_h2h, Wh_bf);
    conv_wut<<<dim3(2048), 256, 0, stream>>>(W_lstm, U_lstm, WU_t);
    gemm_proj<<<dim3(4, 512), 256, 0, stream>>>(x_bf, Wt_bf, proj_bf);
    for (int t = 0; t < T_; ++t) {
        e_kernel<<<dim3(8, 128), 256, 0, stream>>>(proj_bf, hp_buf, W_score, e_buf);
        ctx_kernel<<<dim3(2, 128), 512, 0, stream>>>(e_buf, x_bf, inp_bf);
        z_gemm<<<dim3(16), 256, 0, stream>>>(inp_bf, WU_t, z_buf);
        gates_kernel<<<dim3(128), 512, 0, stream>>>(z_buf, text, W_lstm, b_lstm,
                                                    c, h, hs + (size_t)t * (B_ * H_), inp_bf, t);
        if (t < T_ - 1)
            hp_kernel<<<dim3(2, 128), 256, 0, stream>>>(h, Wh_bf, b_h2h, hp_buf);
    }
    gen_probs<<<dim3(B_ * T_), 64, 0, stream>>>(hs, W_gen, b_gen, out);
}